// Round 10
// baseline (175.510 us; speedup 1.0000x reference)
//
#include <hip/hip_runtime.h>

#define B_    1024
#define T_    2048
#define SEAS_ 24
#define C_    6
#define W_    1977   // T - OS - IS + 1
#define SFW_  2096   // seas_full width
#define CH_   120    // chunk length (multiple of 24)
#define NCH_  17     // chunks c=0..15: 120 steps; c=16: 127 steps

typedef float vf2 __attribute__((ext_vector_type(2)));

__device__ __forceinline__ float frcp(float x) { return __builtin_amdgcn_rcpf(x); }

// One 24-step block (t = t0..t0+23, t0 % 24 == 1). xv[j] = x[t0+j].
// pos sequence: j<23 -> j+1, j=23 -> 0. Same arithmetic as the monolithic scan.
template <bool STORE>
__device__ __forceinline__ void es_block24(
    const float* __restrict__ xv, float* __restrict__ s,
    float lev_a, float oma, float seas_b, float omb, float& lev,
    float* __restrict__ levp, float* __restrict__ nsp)
{
    float ar[24], lv[24];
    #pragma unroll
    for (int j = 0; j < 24; ++j) {
        const int pos = (j + 1 < 24) ? (j + 1) : 0;
        ar[j] = lev_a * (xv[j] * frcp(s[pos]));
    }
    #pragma unroll
    for (int j = 0; j < 24; ++j) {                   // serial lev chain
        lev = __builtin_fmaf(oma, lev, ar[j]);
        lv[j] = lev;
    }
    #pragma unroll
    for (int j = 0; j < 24; ++j) {                   // independent seasonal updates
        const int pos = (j + 1 < 24) ? (j + 1) : 0;
        float ns = __builtin_fmaf(omb, s[pos], seas_b * (xv[j] * frcp(lv[j])));
        s[pos] = ns;
        if (STORE) {
            levp[(size_t)j * B_] = lv[j];
            nsp[(size_t)j * B_]  = ns;
        }
    }
}

// ---------------- transpose x[b][t] -> xT[t][b] (coalesced both sides) ----------------
__global__ __launch_bounds__(256) void transposeX_kernel(
    const float* __restrict__ x, float* __restrict__ xT)
{
    __shared__ float tile[32][33];
    int bb = blockIdx.x * 32;                        // b tile
    int bt = blockIdx.y * 32;                        // t tile
    int tx = threadIdx.x, ty = threadIdx.y;          // (32, 8)
    #pragma unroll
    for (int r = 0; r < 32; r += 8)
        tile[ty + r][tx] = x[(size_t)(bb + ty + r) * T_ + bt + tx];
    __syncthreads();
    #pragma unroll
    for (int r = 0; r < 32; r += 8)
        xT[(size_t)(bt + ty + r) * B_ + bb + tx] = tile[tx][ty + r];
}

// ---------------- Phase 1: state-only sequential scan over xT, coalesced loads --------
// Runs t = 1..1920; saves (s[0..23], lev) after t = 120c into state[c-1][slot][b].
__global__ __launch_bounds__(64) void scan_phase1(
    const float* __restrict__ xT, const float* __restrict__ lev_sms,
    const float* __restrict__ seas_sms, const float* __restrict__ seasonalities,
    const int* __restrict__ idxs, float* __restrict__ state)
{
    int b = blockIdx.x * 64 + threadIdx.x;
    const float* xTb = xT + b;                       // column b, stride B_

    int id = idxs[b];
    float lev_a  = 1.0f / (1.0f + __expf(-lev_sms[id]));
    float seas_b = 1.0f / (1.0f + __expf(-seas_sms[id]));
    float oma = 1.0f - lev_a, omb = 1.0f - seas_b;

    float s[SEAS_];
    #pragma unroll
    for (int j = 0; j < SEAS_; ++j) s[j] = __expf(seasonalities[id * SEAS_ + j]);

    float lev = xTb[0] * frcp(s[0]);                 // lev0 = x[0]/s0[0]

    float xv[24], xn[24];
    #pragma unroll
    for (int j = 0; j < 24; ++j) xv[j] = xTb[(size_t)(1 + j) * B_];

    for (int k = 0; k < 80; ++k) {                   // blocks t = 24k+1 .. 24k+24
        int t0 = 1 + k * 24;
        if (k < 79) {
            #pragma unroll
            for (int j = 0; j < 24; ++j) xn[j] = xTb[(size_t)(t0 + 24 + j) * B_];
        }
        es_block24<false>(xv, s, lev_a, oma, seas_b, omb, lev, nullptr, nullptr);
        if (((k + 1) % 5) == 0) {                    // t = 24(k+1) = 120c done
            int c = (k + 1) / 5 - 1;                 // 0..15
            float* st = state + (size_t)c * 25 * B_ + b;
            #pragma unroll
            for (int j = 0; j < SEAS_; ++j) st[(size_t)j * B_] = s[j];
            st[(size_t)24 * B_] = lev;
        }
        #pragma unroll
        for (int j = 0; j < 24; ++j) xv[j] = xn[j];
    }
}

// ---------------- Phase 2: 17 exact chunks in parallel, heavy stores -------------------
// Chunk c: t in [120c+1, min(120(c+1), 2047)] (c=16 adds the 7-step tail to t=2047).
__global__ __launch_bounds__(64) void scan_phase2(
    const float* __restrict__ xT, const float* __restrict__ lev_sms,
    const float* __restrict__ seas_sms, const float* __restrict__ seasonalities,
    const int* __restrict__ idxs, const float* __restrict__ state,
    float* __restrict__ levT, float* __restrict__ nsT)
{
    int b = blockIdx.x * 64 + threadIdx.x;
    int c = blockIdx.y;
    const float* xTb = xT + b;

    int id = idxs[b];
    float lev_a  = 1.0f / (1.0f + __expf(-lev_sms[id]));
    float seas_b = 1.0f / (1.0f + __expf(-seas_sms[id]));
    float oma = 1.0f - lev_a, omb = 1.0f - seas_b;

    float s[SEAS_];
    float lev;
    if (c == 0) {
        #pragma unroll
        for (int j = 0; j < SEAS_; ++j) s[j] = __expf(seasonalities[id * SEAS_ + j]);
        lev = xTb[0] * frcp(s[0]);                   // lev0 (same ops as phase 1)
        levT[b] = lev;                               // row 0
    } else {
        const float* st = state + (size_t)(c - 1) * 25 * B_ + b;
        #pragma unroll
        for (int j = 0; j < SEAS_; ++j) s[j] = st[(size_t)j * B_];
        lev = st[(size_t)24 * B_];
    }

    int tb = 120 * c + 1;
    float xv[24], xn[24];
    #pragma unroll
    for (int j = 0; j < 24; ++j) xv[j] = xTb[(size_t)(tb + j) * B_];

    float* levp = levT + (size_t)tb * B_ + b;
    float* nsp  = nsT  + (size_t)(tb - 1) * B_ + b;

    #pragma unroll
    for (int kb = 0; kb < 5; ++kb) {                 // 5 blocks of 24 steps
        int t0 = tb + kb * 24;
        int nsteps = (c == NCH_ - 1 && kb == 4) ? 7 : 24;   // next-prefetch count
        #pragma unroll
        for (int j = 0; j < 24; ++j) {
            if (j < nsteps) xn[j] = xTb[(size_t)(t0 + 24 + j) * B_];
        }
        es_block24<true>(xv, s, lev_a, oma, seas_b, omb, lev, levp, nsp);
        levp += (size_t)24 * B_;
        nsp  += (size_t)24 * B_;
        #pragma unroll
        for (int j = 0; j < 24; ++j) xv[j] = xn[j];
    }
    if (c == NCH_ - 1) {                             // tail t = 2041..2047
        #pragma unroll
        for (int j = 0; j < 7; ++j) {
            const int pos = j + 1;
            float xi    = xv[j];
            float ratio = xi * frcp(s[pos]);
            float nl    = __builtin_fmaf(oma, lev, lev_a * ratio);
            float ns    = __builtin_fmaf(omb, s[pos], seas_b * (xi * frcp(nl)));
            s[pos] = ns;
            lev = nl;
            levp[0] = nl;  levp += B_;
            nsp[0]  = ns;  nsp  += B_;
        }
    }
}

// ---------------- transpose levT[t][b] -> out_levs[b][t] ----------------
__global__ __launch_bounds__(256) void transposeL_kernel(
    const float* __restrict__ levT, float* __restrict__ out)
{
    __shared__ float tile[32][33];
    int bt = blockIdx.y * 32;
    int bb = blockIdx.x * 32;
    int tx = threadIdx.x, ty = threadIdx.y;          // (32, 8)
    #pragma unroll
    for (int r = 0; r < 32; r += 8)
        tile[ty + r][tx] = levT[(size_t)(bt + ty + r) * B_ + bb + tx];
    __syncthreads();
    #pragma unroll
    for (int r = 0; r < 32; r += 8)
        out[(size_t)(bb + ty + r) * T_ + bt + tx] = tile[tx][ty + r];
}

// ---------------- transpose nsT -> out_seas[b][u], u in [0, 2096) ----------------
// u<25: head = exp(init_seas[idxs[b]][u<24?u:0]); u in [25,2072): row u-25;
// u in [2072,2096): row u-49 (seasonal tail repeat).
__global__ __launch_bounds__(256) void transposeS_kernel(
    const float* __restrict__ nsT, const float* __restrict__ seasonalities,
    const int* __restrict__ idxs, float* __restrict__ out_seas)
{
    __shared__ float tile[32][33];
    int bu = blockIdx.y * 32;
    int bb = blockIdx.x * 32;
    int tx = threadIdx.x, ty = threadIdx.y;
    int id = idxs[bb + tx];
    #pragma unroll
    for (int r = 0; r < 32; r += 8) {
        int u = bu + ty + r;
        if (u < 25) {
            tile[ty + r][tx] = __expf(seasonalities[id * SEAS_ + (u < 24 ? u : 0)]);
        } else if (u < SFW_) {
            int rr = u - 25 - (u >= 2072 ? 24 : 0);
            tile[ty + r][tx] = nsT[(size_t)rr * B_ + bb + tx];
        }
    }
    __syncthreads();
    #pragma unroll
    for (int r = 0; r < 32; r += 8) {
        int u = bu + tx;
        if (u < SFW_)
            out_seas[(size_t)(bb + ty + r) * SFW_ + u] = tile[tx][ty + r];
    }
}

// ---------------- window materialization (243 MB, write-bound) ----------------
__global__ __launch_bounds__(256) void win_kernel(
    const float* __restrict__ x, const float* __restrict__ levs,
    const float* __restrict__ seasF, const float* __restrict__ info_cat,
    vf2* __restrict__ out)
{
    int w  = blockIdx.y;
    int e2 = blockIdx.x * 256 + threadIdx.x;         // 0..15359 == B*15
    int b  = e2 / 15;
    int j  = e2 - b * 15;
    vf2 v;
    if (j < 12) {
        float inv = frcp(levs[b * T_ + w + 23]);
        int t = w + 2 * j;
        float sa = seasF[b * SFW_ + t];
        float sb = seasF[b * SFW_ + t + 1];
        v.x = x[b * T_ + t]     * frcp(sa) * inv;
        v.y = x[b * T_ + t + 1] * frcp(sb) * inv;
    } else {
        int c = 2 * (j - 12);
        v.x = info_cat[b * C_ + c];
        v.y = info_cat[b * C_ + c + 1];
    }
    __builtin_nontemporal_store(v, &out[(size_t)w * 15360 + e2]);
}

// ---------------- msld: mean_b (logL[i+2] - 2 logL[i+1] + logL[i])^2 ----------------
__global__ __launch_bounds__(256) void msld_kernel(
    const float* __restrict__ levT, float* __restrict__ out)
{
    int i = blockIdx.x;                              // 0..2045
    const float* r0 = levT + (size_t)i * B_;
    float ssum = 0.0f;
    #pragma unroll
    for (int r = 0; r < 4; ++r) {
        int b = threadIdx.x + 256 * r;
        float l0 = __logf(r0[b]);
        float l1 = __logf(r0[b + B_]);
        float l2 = __logf(r0[b + 2 * B_]);
        float d  = l2 - 2.0f * l1 + l0;
        ssum = __builtin_fmaf(d, d, ssum);
    }
    #pragma unroll
    for (int off = 32; off > 0; off >>= 1) ssum += __shfl_down(ssum, off);
    __shared__ float partial[4];
    int wid = threadIdx.x >> 6;
    if ((threadIdx.x & 63) == 0) partial[wid] = ssum;
    __syncthreads();
    if (threadIdx.x == 0)
        out[i] = (partial[0] + partial[1] + partial[2] + partial[3]) * (1.0f / 1024.0f);
}

extern "C" void kernel_launch(void* const* d_in, const int* in_sizes, int n_in,
                              void* d_out, int out_size, void* d_ws, size_t ws_size,
                              hipStream_t stream)
{
    const float* train    = (const float*)d_in[0];
    const float* info_cat = (const float*)d_in[3];
    const float* lev_sms  = (const float*)d_in[4];
    const float* seas_sms = (const float*)d_in[5];
    const float* seasonal = (const float*)d_in[6];
    const int*   idxs     = (const int*)d_in[7];

    float* out      = (float*)d_out;
    float* out_ib   = out;                               // W*B*30
    float* out_levs = out + (size_t)W_ * B_ * 30;        // B*2048
    float* out_seas = out_levs + (size_t)B_ * T_;        // B*2096
    float* out_msld = out_seas + (size_t)B_ * SFW_;      // 2046

    float* ws   = (float*)d_ws;
    float* levT = ws;                                    // 2048*1024 floats
    float* nsT  = ws + (size_t)T_ * B_;                  // 2047*1024 floats

    // Scratch parked in out_ib's head: state (16*25*1024) then xT (2048*1024).
    // Both fully consumed before win_kernel overwrites out_ib (stream-ordered).
    float* state = out_ib;                               // 409,600 floats
    float* xT    = out_ib + 512 * 1024;                  // 2,097,152 floats (ends ~10.4MB)

    transposeX_kernel<<<dim3(B_ / 32, T_ / 32), dim3(32, 8), 0, stream>>>(train, xT);

    scan_phase1<<<B_ / 64, 64, 0, stream>>>(xT, lev_sms, seas_sms, seasonal, idxs,
                                            state);

    scan_phase2<<<dim3(B_ / 64, NCH_), 64, 0, stream>>>(xT, lev_sms, seas_sms,
                                                        seasonal, idxs, state, levT, nsT);

    msld_kernel<<<2046, 256, 0, stream>>>(levT, out_msld);

    dim3 tb(32, 8);
    transposeL_kernel<<<dim3(B_ / 32, T_ / 32), tb, 0, stream>>>(levT, out_levs);
    transposeS_kernel<<<dim3(B_ / 32, (SFW_ + 31) / 32), tb, 0, stream>>>(
        nsT, seasonal, idxs, out_seas);

    dim3 g2(60, W_);
    win_kernel<<<g2, 256, 0, stream>>>(train, out_levs, out_seas, info_cat, (vf2*)out_ib);
}

// Round 11
// 148.506 us; speedup vs baseline: 1.1818x; 1.1818x over previous
//
#include <hip/hip_runtime.h>

#define B_    1024
#define T_    2048
#define SEAS_ 24
#define C_    6
#define W_    1977   // T - OS - IS + 1
#define SFW_  2096   // seas_full width
#define CH_   120    // chunk length (multiple of 24)
#define NCH_  17     // chunks c=0..15: 120 steps; c=16: 127 steps

typedef float vf2 __attribute__((ext_vector_type(2)));

__device__ __forceinline__ float frcp(float x) { return __builtin_amdgcn_rcpf(x); }
__device__ __forceinline__ float getc(const float4& v, int c) {
    return c == 0 ? v.x : c == 1 ? v.y : c == 2 ? v.z : v.w;   // c is compile-time
}

// One 24-step block (steps t = 24k+1 .. 24k+24; xv = x[24k .. 24k+27], element e = j+1).
// ILP-exposed: (1) 24 independent ratios, (2) serial 24-FMA lev chain, (3) 24 independent
// seasonal updates. Same arithmetic as the monolithic scan.
template <bool STORE>
__device__ __forceinline__ void es_block24(
    const float4* __restrict__ xv, float* __restrict__ s,
    float lev_a, float oma, float seas_b, float omb, float& lev,
    float* __restrict__ levp, float* __restrict__ nsp)
{
    float ar[24], lv[24];
    #pragma unroll
    for (int j = 0; j < 24; ++j) {
        const int e = j + 1, pos = (j + 1 < 24) ? (j + 1) : 0;
        ar[j] = lev_a * (getc(xv[e >> 2], e & 3) * frcp(s[pos]));
    }
    #pragma unroll
    for (int j = 0; j < 24; ++j) {                   // serial lev chain
        lev = __builtin_fmaf(oma, lev, ar[j]);
        lv[j] = lev;
    }
    #pragma unroll
    for (int j = 0; j < 24; ++j) {                   // independent seasonal updates
        const int e = j + 1, pos = (j + 1 < 24) ? (j + 1) : 0;
        float xi = getc(xv[e >> 2], e & 3);
        float ns = __builtin_fmaf(omb, s[pos], seas_b * (xi * frcp(lv[j])));
        s[pos] = ns;
        if (STORE) {
            levp[(size_t)j * B_] = lv[j];
            nsp[(size_t)j * B_]  = ns;
        }
    }
}

// ---------------- Phase 1: state-only sequential scan, max-VGPR single wave ------------
// __launch_bounds__(64, 1): 1 wave/EU floor -> compiler may keep ~512 VGPRs, so the
// ping-pong prefetch buffers stay RESIDENT and loads stay hoisted (not sunk to use).
// Runs t = 1..1920; saves (s[0..23], lev) after t = 120c into state[c-1][slot][b].
__global__ __launch_bounds__(64, 1) void scan_phase1(
    const float* __restrict__ x, const float* __restrict__ lev_sms,
    const float* __restrict__ seas_sms, const float* __restrict__ seasonalities,
    const int* __restrict__ idxs, float* __restrict__ state)
{
    int b = blockIdx.x * 64 + threadIdx.x;
    const float4* xr4 = (const float4*)(x + (size_t)b * T_);

    int id = idxs[b];
    float lev_a  = 1.0f / (1.0f + __expf(-lev_sms[id]));
    float seas_b = 1.0f / (1.0f + __expf(-seas_sms[id]));
    float oma = 1.0f - lev_a, omb = 1.0f - seas_b;

    float s[SEAS_];
    #pragma unroll
    for (int j = 0; j < SEAS_; ++j) s[j] = __expf(seasonalities[id * SEAS_ + j]);

    float4 A[7], Bv[7];
    #pragma unroll
    for (int q = 0; q < 7; ++q) A[q]  = xr4[q];          // block 0: t = 0..27
    #pragma unroll
    for (int q = 0; q < 7; ++q) Bv[q] = xr4[6 + q];      // block 1: t = 24..51

    float lev = getc(A[0], 0) * frcp(s[0]);              // lev0

    for (int k = 0; k < 80; k += 2) {
        es_block24<false>(A, s, lev_a, oma, seas_b, omb, lev, nullptr, nullptr);
        if (((k + 1) % 5) == 0) {                        // boundary t = 24(k+1)
            int c = (k + 1) / 5 - 1;
            float* st = state + (size_t)c * 25 * B_ + b;
            #pragma unroll
            for (int j = 0; j < SEAS_; ++j) st[(size_t)j * B_] = s[j];
            st[(size_t)24 * B_] = lev;
        }
        if (k + 2 < 80) {                                // refill A for block k+2
            const float4* nb = xr4 + 6 * (k + 2);
            #pragma unroll
            for (int q = 0; q < 7; ++q) A[q] = nb[q];
        }
        es_block24<false>(Bv, s, lev_a, oma, seas_b, omb, lev, nullptr, nullptr);
        if (((k + 2) % 5) == 0) {                        // boundary t = 24(k+2)
            int c = (k + 2) / 5 - 1;
            float* st = state + (size_t)c * 25 * B_ + b;
            #pragma unroll
            for (int j = 0; j < SEAS_; ++j) st[(size_t)j * B_] = s[j];
            st[(size_t)24 * B_] = lev;
        }
        if (k + 3 < 80) {                                // refill B for block k+3
            const float4* nb = xr4 + 6 * (k + 3);
            #pragma unroll
            for (int q = 0; q < 7; ++q) Bv[q] = nb[q];
        }
    }
}

// ---------------- Phase 2: 17 exact chunks in parallel, heavy stores -------------------
// Chunk c: t in [120c+1, min(120(c+1), 2047)] (c=16 adds the 7-step tail to t=2047).
__global__ __launch_bounds__(64, 1) void scan_phase2(
    const float* __restrict__ x, const float* __restrict__ lev_sms,
    const float* __restrict__ seas_sms, const float* __restrict__ seasonalities,
    const int* __restrict__ idxs, const float* __restrict__ state,
    float* __restrict__ levT, float* __restrict__ nsT)
{
    int b = blockIdx.x * 64 + threadIdx.x;
    int c = blockIdx.y;
    const float4* xr4 = (const float4*)(x + (size_t)b * T_);

    int id = idxs[b];
    float lev_a  = 1.0f / (1.0f + __expf(-lev_sms[id]));
    float seas_b = 1.0f / (1.0f + __expf(-seas_sms[id]));
    float oma = 1.0f - lev_a, omb = 1.0f - seas_b;

    float s[SEAS_];
    float lev;
    if (c == 0) {
        #pragma unroll
        for (int j = 0; j < SEAS_; ++j) s[j] = __expf(seasonalities[id * SEAS_ + j]);
        lev = getc(xr4[0], 0) * frcp(s[0]);              // lev0 (same ops as phase 1)
        levT[b] = lev;                                   // row 0
    } else {
        const float* st = state + (size_t)(c - 1) * 25 * B_ + b;
        #pragma unroll
        for (int j = 0; j < SEAS_; ++j) s[j] = st[(size_t)j * B_];
        lev = st[(size_t)24 * B_];
    }

    float4 xv[7], xn[7];
    const float4* base0 = xr4 + 30 * c;                  // t = 120c ..
    #pragma unroll
    for (int q = 0; q < 7; ++q) xv[q] = base0[q];

    float* levp = levT + (size_t)(120 * c + 1) * B_ + b;
    float* nsp  = nsT  + (size_t)(120 * c) * B_ + b;

    #pragma unroll
    for (int kb = 0; kb < 5; ++kb) {                     // 5 blocks of 24 steps
        const float4* nb = xr4 + 30 * c + 6 * (kb + 1);
        if (c == NCH_ - 1 && kb == 4) {                  // next base 510: only 2 in-bounds
            xn[0] = nb[0]; xn[1] = nb[1];
        } else {
            #pragma unroll
            for (int q = 0; q < 7; ++q) xn[q] = nb[q];
        }
        es_block24<true>(xv, s, lev_a, oma, seas_b, omb, lev, levp, nsp);
        levp += (size_t)24 * B_;
        nsp  += (size_t)24 * B_;
        #pragma unroll
        for (int q = 0; q < 7; ++q) xv[q] = xn[q];
    }
    if (c == NCH_ - 1) {                                 // tail t = 2041..2047
        #pragma unroll
        for (int j = 0; j < 7; ++j) {
            const int e = j + 1, pos = j + 1;
            float xi    = getc(xv[e >> 2], e & 3);
            float ratio = xi * frcp(s[pos]);
            float nl    = __builtin_fmaf(oma, lev, lev_a * ratio);
            float ns    = __builtin_fmaf(omb, s[pos], seas_b * (xi * frcp(nl)));
            s[pos] = ns;
            lev = nl;
            levp[0] = nl;  levp += B_;
            nsp[0]  = ns;  nsp  += B_;
        }
    }
}

// ---------------- transpose levT[t][b] -> out_levs[b][t] ----------------
__global__ __launch_bounds__(256) void transposeL_kernel(
    const float* __restrict__ levT, float* __restrict__ out)
{
    __shared__ float tile[32][33];
    int bt = blockIdx.y * 32;
    int bb = blockIdx.x * 32;
    int tx = threadIdx.x, ty = threadIdx.y;          // (32, 8)
    #pragma unroll
    for (int r = 0; r < 32; r += 8)
        tile[ty + r][tx] = levT[(size_t)(bt + ty + r) * B_ + bb + tx];
    __syncthreads();
    #pragma unroll
    for (int r = 0; r < 32; r += 8)
        out[(size_t)(bb + ty + r) * T_ + bt + tx] = tile[tx][ty + r];
}

// ---------------- transpose nsT -> out_seas[b][u], u in [0, 2096) ----------------
// u<25: head = exp(init_seas[idxs[b]][u<24?u:0]); u in [25,2072): row u-25;
// u in [2072,2096): row u-49 (seasonal tail repeat).
__global__ __launch_bounds__(256) void transposeS_kernel(
    const float* __restrict__ nsT, const float* __restrict__ seasonalities,
    const int* __restrict__ idxs, float* __restrict__ out_seas)
{
    __shared__ float tile[32][33];
    int bu = blockIdx.y * 32;
    int bb = blockIdx.x * 32;
    int tx = threadIdx.x, ty = threadIdx.y;
    int id = idxs[bb + tx];
    #pragma unroll
    for (int r = 0; r < 32; r += 8) {
        int u = bu + ty + r;
        if (u < 25) {
            tile[ty + r][tx] = __expf(seasonalities[id * SEAS_ + (u < 24 ? u : 0)]);
        } else if (u < SFW_) {
            int rr = u - 25 - (u >= 2072 ? 24 : 0);
            tile[ty + r][tx] = nsT[(size_t)rr * B_ + bb + tx];
        }
    }
    __syncthreads();
    #pragma unroll
    for (int r = 0; r < 32; r += 8) {
        int u = bu + tx;
        if (u < SFW_)
            out_seas[(size_t)(bb + ty + r) * SFW_ + u] = tile[tx][ty + r];
    }
}

// ---------------- window materialization (243 MB, write-bound) ----------------
__global__ __launch_bounds__(256) void win_kernel(
    const float* __restrict__ x, const float* __restrict__ levs,
    const float* __restrict__ seasF, const float* __restrict__ info_cat,
    vf2* __restrict__ out)
{
    int w  = blockIdx.y;
    int e2 = blockIdx.x * 256 + threadIdx.x;         // 0..15359 == B*15
    int b  = e2 / 15;
    int j  = e2 - b * 15;
    vf2 v;
    if (j < 12) {
        float inv = frcp(levs[b * T_ + w + 23]);
        int t = w + 2 * j;
        float sa = seasF[b * SFW_ + t];
        float sb = seasF[b * SFW_ + t + 1];
        v.x = x[b * T_ + t]     * frcp(sa) * inv;
        v.y = x[b * T_ + t + 1] * frcp(sb) * inv;
    } else {
        int c = 2 * (j - 12);
        v.x = info_cat[b * C_ + c];
        v.y = info_cat[b * C_ + c + 1];
    }
    __builtin_nontemporal_store(v, &out[(size_t)w * 15360 + e2]);
}

// ---------------- msld: mean_b (logL[i+2] - 2 logL[i+1] + logL[i])^2 ----------------
__global__ __launch_bounds__(256) void msld_kernel(
    const float* __restrict__ levT, float* __restrict__ out)
{
    int i = blockIdx.x;                              // 0..2045
    const float* r0 = levT + (size_t)i * B_;
    float ssum = 0.0f;
    #pragma unroll
    for (int r = 0; r < 4; ++r) {
        int b = threadIdx.x + 256 * r;
        float l0 = __logf(r0[b]);
        float l1 = __logf(r0[b + B_]);
        float l2 = __logf(r0[b + 2 * B_]);
        float d  = l2 - 2.0f * l1 + l0;
        ssum = __builtin_fmaf(d, d, ssum);
    }
    #pragma unroll
    for (int off = 32; off > 0; off >>= 1) ssum += __shfl_down(ssum, off);
    __shared__ float partial[4];
    int wid = threadIdx.x >> 6;
    if ((threadIdx.x & 63) == 0) partial[wid] = ssum;
    __syncthreads();
    if (threadIdx.x == 0)
        out[i] = (partial[0] + partial[1] + partial[2] + partial[3]) * (1.0f / 1024.0f);
}

extern "C" void kernel_launch(void* const* d_in, const int* in_sizes, int n_in,
                              void* d_out, int out_size, void* d_ws, size_t ws_size,
                              hipStream_t stream)
{
    const float* train    = (const float*)d_in[0];
    const float* info_cat = (const float*)d_in[3];
    const float* lev_sms  = (const float*)d_in[4];
    const float* seas_sms = (const float*)d_in[5];
    const float* seasonal = (const float*)d_in[6];
    const int*   idxs     = (const int*)d_in[7];

    float* out      = (float*)d_out;
    float* out_ib   = out;                               // W*B*30
    float* out_levs = out + (size_t)W_ * B_ * 30;        // B*2048
    float* out_seas = out_levs + (size_t)B_ * T_;        // B*2096
    float* out_msld = out_seas + (size_t)B_ * SFW_;      // 2046

    float* ws   = (float*)d_ws;
    float* levT = ws;                                    // 2048*1024 floats
    float* nsT  = ws + (size_t)T_ * B_;                  // 2047*1024 floats

    // Exact boundary states live in the head of out_ib: written by phase1, read by
    // phase2, later overwritten by win_kernel (stream-ordered, race-free).
    float* state = out_ib;                               // 16*25*1024 floats

    scan_phase1<<<B_ / 64, 64, 0, stream>>>(train, lev_sms, seas_sms, seasonal, idxs,
                                            state);

    scan_phase2<<<dim3(B_ / 64, NCH_), 64, 0, stream>>>(train, lev_sms, seas_sms,
                                                        seasonal, idxs, state, levT, nsT);

    msld_kernel<<<2046, 256, 0, stream>>>(levT, out_msld);

    dim3 tb(32, 8);
    transposeL_kernel<<<dim3(B_ / 32, T_ / 32), tb, 0, stream>>>(levT, out_levs);
    transposeS_kernel<<<dim3(B_ / 32, (SFW_ + 31) / 32), tb, 0, stream>>>(
        nsT, seasonal, idxs, out_seas);

    dim3 g2(60, W_);
    win_kernel<<<g2, 256, 0, stream>>>(train, out_levs, out_seas, info_cat, (vf2*)out_ib);
}